// Round 8
// baseline (1469.744 us; speedup 1.0000x reference)
//
#include <hip/hip_runtime.h>
#include <hip/hip_bf16.h>
#include <cstdint>

// MoE top-2 of 8, N=32768 tokens, D=1024.
// fp32 -> (bf16 hi, lo) split; out = hi*Wh + hi*Wl + lo*Wh, K_eff = 3*1024.
// Grouped GEMM: 256x256 tile, BK=32, 8 waves (2Mx4N), 4-deep LDS ring,
// counted vmcnt(8) (T4), 2 phases/K-step (T3), 2-bit XOR LDS swizzle (T2),
// setprio around MFMA (T5), XCD-chunked block swizzle (T1).
// Two passes (slot0 write, slot1 +=), no atomics.

#define N_TOK 32768
#define DIM   1024
#define NEXP  8
#define NT2   136           // max sum_e ceil(n_e/256) = 135; padded

typedef __attribute__((ext_vector_type(8))) short short8;   // 8 bf16
typedef __attribute__((ext_vector_type(4))) float f32x4;
typedef unsigned short u16;

struct Ctrl {
  int counts[16];      // [slot][expert] -- zeroed by k_convert_w each launch
  int cursors[16];
  int ntiles[2];
  int pad[30];
  int4 table[2 * NT2]; // {expert, start_in_slot_list, rows, 0}
};

__device__ __forceinline__ void gload_lds16(void* lds, const void* g) {
  __builtin_amdgcn_global_load_lds(
      (const __attribute__((address_space(1))) void*)g,
      (__attribute__((address_space(3))) void*)lds, 16, 0, 0);
}

// split: hi = truncate-to-bf16(x); lo = truncate-to-bf16(x - hi)
__device__ __forceinline__ void splitf(float f, u16& h, u16& l) {
  uint32_t u = __float_as_uint(f);
  h = (u16)(u >> 16);
  float r = f - __uint_as_float(u & 0xFFFF0000u);   // exact in f32
  l = (u16)(__float_as_uint(r) >> 16);
}

// ---------------- expert weight conversion (+ ctrl zero) ----------------
extern "C" __global__ __launch_bounds__(256) void k_convert_w(
    const float4* __restrict__ W, ushort4* __restrict__ Wh,
    ushort4* __restrict__ Wl, int* __restrict__ counts) {
  if (blockIdx.x == 0 && threadIdx.x < 16) counts[threadIdx.x] = 0;
  const int total = NEXP * DIM * DIM / 4;
  for (int i = blockIdx.x * 256 + threadIdx.x; i < total; i += gridDim.x * 256) {
    float4 v = W[i];
    u16 hx, lx, hy, ly, hz, lz, hw, lw;
    splitf(v.x, hx, lx); splitf(v.y, hy, ly);
    splitf(v.z, hz, lz); splitf(v.w, hw, lw);
    Wh[i] = make_ushort4(hx, hy, hz, hw);
    Wl[i] = make_ushort4(lx, ly, lz, lw);
  }
}

// ---------------- gating + x conversion (fused) ----------------
extern "C" __global__ __launch_bounds__(256) void k_gate(
    const float* __restrict__ x, const float* __restrict__ gW,
    const float* __restrict__ gb, u16* __restrict__ xh, u16* __restrict__ xl,
    float* __restrict__ wts, int* __restrict__ eids, int* __restrict__ counts) {
  __shared__ float4 gwl[NEXP * 256];
  __shared__ int cnt[16];
  int tid = threadIdx.x;
  for (int i = tid; i < NEXP * 256; i += 256) gwl[i] = ((const float4*)gW)[i];
  if (tid < 16) cnt[tid] = 0;
  __syncthreads();

  float gbr[NEXP];
#pragma unroll
  for (int e = 0; e < NEXP; ++e) gbr[e] = gb[e];

  int lane = tid & 63, wid = tid >> 6;
  int wave = blockIdx.x * 4 + wid;
  for (int t = wave; t < N_TOK; t += 2048) {
    const float4* xr = (const float4*)(x + (size_t)t * DIM);
    float acc[NEXP] = {0,0,0,0,0,0,0,0};
    float4 xv[4];
#pragma unroll
    for (int j = 0; j < 4; ++j) {
      float4 v = xr[j * 64 + lane];
      xv[j] = v;
#pragma unroll
      for (int e = 0; e < NEXP; ++e) {
        float4 g = gwl[e * 256 + j * 64 + lane];
        acc[e] += v.x * g.x + v.y * g.y + v.z * g.z + v.w * g.w;
      }
    }
#pragma unroll
    for (int off = 32; off > 0; off >>= 1)
#pragma unroll
      for (int e = 0; e < NEXP; ++e) acc[e] += __shfl_xor(acc[e], off, 64);

#pragma unroll
    for (int e = 0; e < NEXP; ++e) acc[e] += gbr[e];

    float m = acc[0];
#pragma unroll
    for (int e = 1; e < NEXP; ++e) m = fmaxf(m, acc[e]);
    float p[NEXP], s = 0.f;
#pragma unroll
    for (int e = 0; e < NEXP; ++e) { p[e] = expf(acc[e] - m); s += p[e]; }
    float inv = 1.f / s;

    int i0 = 0; float b0 = acc[0];
#pragma unroll
    for (int e = 1; e < NEXP; ++e) if (acc[e] > b0) { b0 = acc[e]; i0 = e; }
    int i1 = -1; float b1 = -3.4e38f;
#pragma unroll
    for (int e = 0; e < NEXP; ++e)
      if (e != i0 && acc[e] > b1) { b1 = acc[e]; i1 = e; }

    if (lane == 0) {
      wts[t * 2 + 0] = p[i0] * inv;
      wts[t * 2 + 1] = p[i1] * inv;
      eids[t * 2 + 0] = i0;
      eids[t * 2 + 1] = i1;
      atomicAdd(&cnt[i0], 1);
      atomicAdd(&cnt[8 + i1], 1);
    }
    ushort4* oh = (ushort4*)(xh + (size_t)t * DIM);
    ushort4* ol = (ushort4*)(xl + (size_t)t * DIM);
#pragma unroll
    for (int j = 0; j < 4; ++j) {
      u16 hx, lx, hy, ly, hz, lz, hw, lw;
      splitf(xv[j].x, hx, lx); splitf(xv[j].y, hy, ly);
      splitf(xv[j].z, hz, lz); splitf(xv[j].w, hw, lw);
      oh[j * 64 + lane] = make_ushort4(hx, hy, hz, hw);
      ol[j * 64 + lane] = make_ushort4(lx, ly, lz, lw);
    }
  }
  __syncthreads();
  if (tid < 16) atomicAdd(&counts[tid], cnt[tid]);
}

// ---------------- scan + tile schedule (BM=256) ----------------
extern "C" __global__ void k_scan(Ctrl* ctrl) {
  if (threadIdx.x == 0) {
    for (int s = 0; s < 2; ++s) {
      int off = 0, nt = 0;
      for (int e = 0; e < NEXP; ++e) {
        int c = ctrl->counts[s * 8 + e];
        ctrl->cursors[s * 8 + e] = off;
        int tcnt = (c + 255) >> 8;
        for (int i = 0; i < tcnt; ++i)
          ctrl->table[s * NT2 + nt + i] =
              make_int4(e, off + i * 256, min(256, c - i * 256), 0);
        nt += tcnt; off += c;
      }
      ctrl->ntiles[s] = nt;
    }
  }
}

// ---------------- build per-(slot,expert) token lists ----------------
extern "C" __global__ __launch_bounds__(256) void k_lists(
    const int* __restrict__ eids, int* __restrict__ cursors, int* __restrict__ lists) {
  int t = blockIdx.x * 256 + threadIdx.x;
  int lane = threadIdx.x & 63;
#pragma unroll
  for (int s = 0; s < 2; ++s) {
    int e = eids[t * 2 + s];
#pragma unroll
    for (int ex = 0; ex < NEXP; ++ex) {
      unsigned long long msk = __ballot(e == ex);
      if (msk) {
        int leader = __ffsll((unsigned long long)msk) - 1;
        int base = 0;
        if (lane == leader) base = atomicAdd(&cursors[s * 8 + ex], (int)__popcll(msk));
        base = __shfl(base, leader, 64);
        if (e == ex) {
          int pos = base + (int)__popcll(msk & ((1ull << lane) - 1ull));
          lists[s * N_TOK + pos] = t;
        }
      }
    }
  }
}

// ---------------- grouped GEMM, phase-interleaved schedule ----------------
// 256x256 tile, BK=32 (96 K-steps over 3 terms), 8 waves = 2M x 4N.
// LDS: 4-ring x (A 16KB + B 16KB) = 128KB + tok/wt 2KB.
// T2 swizzle: 16B-slot ^= (row&3) ^ ((row>>2)&3); applied identically on the
// pre-swizzled global source and the ds_read address (LDS dest stays linear).
// Read aliasing is 2-way (free, m136); a 1-bit form would be a 4-way conflict.
extern "C" __global__ __launch_bounds__(512, 2) void k_gemm(
    int slot, const u16* __restrict__ xh, const u16* __restrict__ xl,
    const u16* __restrict__ Wh, const u16* __restrict__ Wl,
    const float* __restrict__ eb, const float* __restrict__ wts,
    const int* __restrict__ lists, const int* __restrict__ ntiles,
    const int4* __restrict__ table, float* __restrict__ out) {
  // T1: bijective XCD-chunked swizzle (grid = 544 = 8 * 68; XCD = blockIdx%8)
  int L = (blockIdx.x & 7) * (NT2 / 2) + (blockIdx.x >> 3);
  int tm = L >> 2, tn = L & 3;
  if (tm >= ntiles[slot]) return;
  int4 ent = table[slot * NT2 + tm];
  int e = ent.x, start = ent.y, rows = ent.z;
  int n0 = tn * 256;

  __shared__ __align__(16) char smemc[4 * 32768];   // ring of 4 K-steps
  __shared__ int   tok_s[256];
  __shared__ float wt_s[256];

  int tid = threadIdx.x, lane = tid & 63, wid = tid >> 6;
  if (tid < 256) {
    int t = 0; float w = 0.f;
    if (tid < rows) { t = lists[slot * N_TOK + start + tid]; w = wts[t * 2 + slot]; }
    tok_s[tid] = t; wt_s[tid] = w;
  }
  __syncthreads();

  // swizzle function of lane (same for staging source and fragment read):
  // f = (lane&3) ^ ((lane>>2)&3) ^ (lane>>4)
  int fsw = ((lane & 3) ^ ((lane >> 2) & 3) ^ (lane >> 4)) << 4;

  // --- staging: lane covers row rr = wid*16 + (lane>>2); global 16B slot = f ---
  int rr = wid * 16 + (lane >> 2);
  unsigned off_a0 = (unsigned)tok_s[rr] * 2048u + fsw;
  unsigned off_a1 = (unsigned)tok_s[128 + rr] * 2048u + fsw;
  unsigned off_b0 = (unsigned)((e << 10) + n0 + rr) * 2048u + fsw;
  unsigned off_b1 = (unsigned)((e << 10) + n0 + 128 + rr) * 2048u + fsw;

  // --- fragment reads: row r = mi*16 + (lane&15), k-slot j = lane>>4 ---
  int wm = wid >> 2, wn = wid & 3;                       // 2M x 4N
  int aoff = wm * 8192 + (lane & 15) * 64 + fsw;
  int boff = wn * 4096 + (lane & 15) * 64 + fsw;

  f32x4 acc[8][4] = {};

  // --- prologue: stage K-steps 0..2 (all term 0) ---
#pragma unroll
  for (int t = 0; t < 3; ++t) {
    const char* sA = (const char*)xh + t * 64;
    const char* sB = (const char*)Wh + t * 64;
    char* dst = smemc + t * 32768;
    gload_lds16(dst +         wid * 1024, sA + off_a0);
    gload_lds16(dst +  8192 + wid * 1024, sA + off_a1);
    gload_lds16(dst + 16384 + wid * 1024, sB + off_b0);
    gload_lds16(dst + 24576 + wid * 1024, sB + off_b1);
  }
  asm volatile("s_waitcnt vmcnt(8)" ::: "memory");
  __builtin_amdgcn_s_barrier();

#pragma unroll 1
  for (int kt = 0; kt < 96; ++kt) {
    int ks = kt + 3; if (ks > 95) ks = 95;    // clamp keeps vmcnt ledger uniform
    int termS = ks >> 5;
    const char* sA = ((termS == 2) ? (const char*)xl : (const char*)xh) + ((ks & 31) << 6);
    const char* sB = ((termS == 1) ? (const char*)Wl : (const char*)Wh) + ((ks & 31) << 6);
    char* dst = smemc + ((kt + 3) & 3) * 32768;
    const char* bufA = smemc + (kt & 3) * 32768;
    const char* bufB = bufA + 16384;

    short8 a[4], b[4];
    // ---- phase 0: M-half 0 ----
    gload_lds16(dst +         wid * 1024, sA + off_a0);
    gload_lds16(dst + 16384 + wid * 1024, sB + off_b0);
    {
      const char* ap = bufA + aoff;
      a[0] = *(const short8*)(ap);
      a[1] = *(const short8*)(ap + 1024);
      a[2] = *(const short8*)(ap + 2048);
      a[3] = *(const short8*)(ap + 3072);
      const char* bp = bufB + boff;
      b[0] = *(const short8*)(bp);
      b[1] = *(const short8*)(bp + 1024);
      b[2] = *(const short8*)(bp + 2048);
      b[3] = *(const short8*)(bp + 3072);
    }
    __builtin_amdgcn_s_barrier();
    asm volatile("s_waitcnt lgkmcnt(0)" ::: "memory");
    __builtin_amdgcn_sched_barrier(0);
    __builtin_amdgcn_s_setprio(1);
#pragma unroll
    for (int mi = 0; mi < 4; ++mi)
#pragma unroll
      for (int ni = 0; ni < 4; ++ni)
        acc[mi][ni] = __builtin_amdgcn_mfma_f32_16x16x32_bf16(
            a[mi], b[ni], acc[mi][ni], 0, 0, 0);
    __builtin_amdgcn_s_setprio(0);
    __builtin_amdgcn_s_barrier();
    // ---- phase 1: M-half 1 (reuse b) ----
    gload_lds16(dst +  8192 + wid * 1024, sA + off_a1);
    gload_lds16(dst + 24576 + wid * 1024, sB + off_b1);
    {
      const char* ap = bufA + aoff + 4096;
      a[0] = *(const short8*)(ap);
      a[1] = *(const short8*)(ap + 1024);
      a[2] = *(const short8*)(ap + 2048);
      a[3] = *(const short8*)(ap + 3072);
    }
    __builtin_amdgcn_s_barrier();
    asm volatile("s_waitcnt lgkmcnt(0)" ::: "memory");
    __builtin_amdgcn_sched_barrier(0);
    __builtin_amdgcn_s_setprio(1);
#pragma unroll
    for (int mi = 0; mi < 4; ++mi)
#pragma unroll
      for (int ni = 0; ni < 4; ++ni)
        acc[4 + mi][ni] = __builtin_amdgcn_mfma_f32_16x16x32_bf16(
            a[mi], b[ni], acc[4 + mi][ni], 0, 0, 0);
    __builtin_amdgcn_s_setprio(0);
    asm volatile("s_waitcnt vmcnt(8)" ::: "memory");   // kt+1 staged; kt+2,kt+3 in flight
    __builtin_amdgcn_s_barrier();
  }

  // ---- epilogue: scatter out[tok] = / += w*(acc+bias) ----
#pragma unroll
  for (int mi = 0; mi < 8; ++mi) {
    int rb = wm * 128 + mi * 16 + (lane >> 4) * 4;
#pragma unroll
    for (int ni = 0; ni < 4; ++ni) {
      int c = n0 + wn * 64 + ni * 16 + (lane & 15);
      float bv = eb[e * DIM + c];
#pragma unroll
      for (int j = 0; j < 4; ++j) {
        int r = rb + j;
        if (r < rows) {
          float v = wt_s[r] * (acc[mi][ni][j] + bv);
          size_t oidx = (size_t)tok_s[r] * DIM + c;
          if (slot == 0) out[oidx] = v;
          else           out[oidx] += v;
        }
      }
    }
  }
}

// ---------------- launch ----------------
extern "C" void kernel_launch(void* const* d_in, const int* in_sizes, int n_in,
                              void* d_out, int out_size, void* d_ws, size_t ws_size,
                              hipStream_t stream) {
  const float* x  = (const float*)d_in[0];
  const float* gW = (const float*)d_in[1];
  const float* gb = (const float*)d_in[2];
  const float* eW = (const float*)d_in[3];
  const float* eb = (const float*)d_in[4];
  float* out = (float*)d_out;

  char* ws = (char*)d_ws;
  size_t o = 0;
  u16* xh = (u16*)(ws + o); o += (size_t)N_TOK * DIM * 2;      //  64 MiB
  u16* xl = (u16*)(ws + o); o += (size_t)N_TOK * DIM * 2;      //  64 MiB
  u16* Wh = (u16*)(ws + o); o += (size_t)NEXP * DIM * DIM * 2; //  16 MiB
  u16* Wl = (u16*)(ws + o); o += (size_t)NEXP * DIM * DIM * 2; //  16 MiB
  float* wts = (float*)(ws + o); o += (size_t)N_TOK * 2 * 4;
  int* eids  = (int*)(ws + o);   o += (size_t)N_TOK * 2 * 4;
  int* lists = (int*)(ws + o);   o += (size_t)2 * N_TOK * 4;
  Ctrl* ctrl = (Ctrl*)(ws + o);  o += sizeof(Ctrl);

  k_convert_w<<<2048, 256, 0, stream>>>((const float4*)eW, (ushort4*)Wh,
                                        (ushort4*)Wl, ctrl->counts);
  k_gate<<<512, 256, 0, stream>>>(x, gW, gb, xh, xl, wts, eids, ctrl->counts);
  k_scan<<<1, 64, 0, stream>>>(ctrl);
  k_lists<<<N_TOK / 256, 256, 0, stream>>>(eids, ctrl->cursors, lists);
  k_gemm<<<NT2 * 4, 512, 0, stream>>>(0, xh, xl, Wh, Wl, eb, wts, lists,
                                      ctrl->ntiles, ctrl->table, out);
  k_gemm<<<NT2 * 4, 512, 0, stream>>>(1, xh, xl, Wh, Wl, eb, wts, lists,
                                      ctrl->ntiles, ctrl->table, out);
}

// Round 9
// 1229.387 us; speedup vs baseline: 1.1955x; 1.1955x over previous
//
#include <hip/hip_runtime.h>
#include <hip/hip_bf16.h>
#include <cstdint>

// MoE top-2 of 8, N=32768 tokens, D=1024.
// fp32 -> (bf16 hi, lo) split; out = hi*Wh + hi*Wl + lo*Wh, K_eff = 3*1024.
// Grouped GEMM: 128x128 tile (multi-block/CU TLP regime, round-2 measured best),
// + minimal 2-phase prefetch: double-buffered LDS, stage(kt+1) issued BEFORE
// compute(kt), ONE __syncthreads per K-step (drains vmcnt -> next buf ready).
// Two passes (slot0 write, slot1 +=), no atomics.

#define N_TOK 32768
#define DIM   1024
#define NEXP  8
#define BM    128
#define BK    32
#define NTM   263           // max sum_e ceil(n_e/128)

typedef __attribute__((ext_vector_type(8))) short short8;   // 8 bf16
typedef __attribute__((ext_vector_type(4))) float f32x4;
typedef unsigned short u16;

struct Ctrl {
  int counts[16];      // [slot][expert] -- zeroed by k_convert_w each launch
  int cursors[16];
  int ntiles[2];
  int pad[30];
  int4 table[2 * NTM]; // {expert, start_in_slot_list, rows, 0}
};

__device__ __forceinline__ void gload_lds16(void* lds, const void* g) {
  __builtin_amdgcn_global_load_lds(
      (const __attribute__((address_space(1))) void*)g,
      (__attribute__((address_space(3))) void*)lds, 16, 0, 0);
}

// split: hi = truncate-to-bf16(x); lo = truncate-to-bf16(x - hi)
__device__ __forceinline__ void splitf(float f, u16& h, u16& l) {
  uint32_t u = __float_as_uint(f);
  h = (u16)(u >> 16);
  float r = f - __uint_as_float(u & 0xFFFF0000u);   // exact in f32
  l = (u16)(__float_as_uint(r) >> 16);
}

// ---------------- expert weight conversion (+ ctrl zero) ----------------
extern "C" __global__ __launch_bounds__(256) void k_convert_w(
    const float4* __restrict__ W, ushort4* __restrict__ Wh,
    ushort4* __restrict__ Wl, int* __restrict__ counts) {
  if (blockIdx.x == 0 && threadIdx.x < 16) counts[threadIdx.x] = 0;
  const int total = NEXP * DIM * DIM / 4;
  for (int i = blockIdx.x * 256 + threadIdx.x; i < total; i += gridDim.x * 256) {
    float4 v = W[i];
    u16 hx, lx, hy, ly, hz, lz, hw, lw;
    splitf(v.x, hx, lx); splitf(v.y, hy, ly);
    splitf(v.z, hz, lz); splitf(v.w, hw, lw);
    Wh[i] = make_ushort4(hx, hy, hz, hw);
    Wl[i] = make_ushort4(lx, ly, lz, lw);
  }
}

// ---------------- gating + x conversion (fused) ----------------
extern "C" __global__ __launch_bounds__(256) void k_gate(
    const float* __restrict__ x, const float* __restrict__ gW,
    const float* __restrict__ gb, u16* __restrict__ xh, u16* __restrict__ xl,
    float* __restrict__ wts, int* __restrict__ eids, int* __restrict__ counts) {
  __shared__ float4 gwl[NEXP * 256];
  __shared__ int cnt[16];
  int tid = threadIdx.x;
  for (int i = tid; i < NEXP * 256; i += 256) gwl[i] = ((const float4*)gW)[i];
  if (tid < 16) cnt[tid] = 0;
  __syncthreads();

  float gbr[NEXP];
#pragma unroll
  for (int e = 0; e < NEXP; ++e) gbr[e] = gb[e];

  int lane = tid & 63, wid = tid >> 6;
  int wave = blockIdx.x * 4 + wid;
  for (int t = wave; t < N_TOK; t += 2048) {
    const float4* xr = (const float4*)(x + (size_t)t * DIM);
    float acc[NEXP] = {0,0,0,0,0,0,0,0};
    float4 xv[4];
#pragma unroll
    for (int j = 0; j < 4; ++j) {
      float4 v = xr[j * 64 + lane];
      xv[j] = v;
#pragma unroll
      for (int e = 0; e < NEXP; ++e) {
        float4 g = gwl[e * 256 + j * 64 + lane];
        acc[e] += v.x * g.x + v.y * g.y + v.z * g.z + v.w * g.w;
      }
    }
#pragma unroll
    for (int off = 32; off > 0; off >>= 1)
#pragma unroll
      for (int e = 0; e < NEXP; ++e) acc[e] += __shfl_xor(acc[e], off, 64);

#pragma unroll
    for (int e = 0; e < NEXP; ++e) acc[e] += gbr[e];

    float m = acc[0];
#pragma unroll
    for (int e = 1; e < NEXP; ++e) m = fmaxf(m, acc[e]);
    float p[NEXP], s = 0.f;
#pragma unroll
    for (int e = 0; e < NEXP; ++e) { p[e] = expf(acc[e] - m); s += p[e]; }
    float inv = 1.f / s;

    int i0 = 0; float b0 = acc[0];
#pragma unroll
    for (int e = 1; e < NEXP; ++e) if (acc[e] > b0) { b0 = acc[e]; i0 = e; }
    int i1 = -1; float b1 = -3.4e38f;
#pragma unroll
    for (int e = 0; e < NEXP; ++e)
      if (e != i0 && acc[e] > b1) { b1 = acc[e]; i1 = e; }

    if (lane == 0) {
      wts[t * 2 + 0] = p[i0] * inv;
      wts[t * 2 + 1] = p[i1] * inv;
      eids[t * 2 + 0] = i0;
      eids[t * 2 + 1] = i1;
      atomicAdd(&cnt[i0], 1);
      atomicAdd(&cnt[8 + i1], 1);
    }
    ushort4* oh = (ushort4*)(xh + (size_t)t * DIM);
    ushort4* ol = (ushort4*)(xl + (size_t)t * DIM);
#pragma unroll
    for (int j = 0; j < 4; ++j) {
      u16 hx, lx, hy, ly, hz, lz, hw, lw;
      splitf(xv[j].x, hx, lx); splitf(xv[j].y, hy, ly);
      splitf(xv[j].z, hz, lz); splitf(xv[j].w, hw, lw);
      oh[j * 64 + lane] = make_ushort4(hx, hy, hz, hw);
      ol[j * 64 + lane] = make_ushort4(lx, ly, lz, lw);
    }
  }
  __syncthreads();
  if (tid < 16) atomicAdd(&counts[tid], cnt[tid]);
}

// ---------------- scan + tile schedule (BM=128) ----------------
extern "C" __global__ void k_scan(Ctrl* ctrl) {
  if (threadIdx.x == 0) {
    for (int s = 0; s < 2; ++s) {
      int off = 0, nt = 0;
      for (int e = 0; e < NEXP; ++e) {
        int c = ctrl->counts[s * 8 + e];
        ctrl->cursors[s * 8 + e] = off;
        int tcnt = (c + BM - 1) >> 7;
        for (int i = 0; i < tcnt; ++i)
          ctrl->table[s * NTM + nt + i] =
              make_int4(e, off + i * BM, min(BM, c - i * BM), 0);
        nt += tcnt; off += c;
      }
      ctrl->ntiles[s] = nt;
    }
  }
}

// ---------------- build per-(slot,expert) token lists ----------------
extern "C" __global__ __launch_bounds__(256) void k_lists(
    const int* __restrict__ eids, int* __restrict__ cursors, int* __restrict__ lists) {
  int t = blockIdx.x * 256 + threadIdx.x;
  int lane = threadIdx.x & 63;
#pragma unroll
  for (int s = 0; s < 2; ++s) {
    int e = eids[t * 2 + s];
#pragma unroll
    for (int ex = 0; ex < NEXP; ++ex) {
      unsigned long long msk = __ballot(e == ex);
      if (msk) {
        int leader = __ffsll((unsigned long long)msk) - 1;
        int base = 0;
        if (lane == leader) base = atomicAdd(&cursors[s * 8 + ex], (int)__popcll(msk));
        base = __shfl(base, leader, 64);
        if (e == ex) {
          int pos = base + (int)__popcll(msk & ((1ull << lane) - 1ull));
          lists[s * N_TOK + pos] = t;
        }
      }
    }
  }
}

// ---------------- grouped GEMM (one slot per launch) ----------------
// 128x128 tile; 96 K-steps (3 split-terms x K=1024, BK=32).
// 2-phase prefetch: stage(kt+1) into buf^1, read+MFMA from buf, ONE sync/step.
extern "C" __global__ __launch_bounds__(256) void k_gemm(
    int slot, const u16* __restrict__ xh, const u16* __restrict__ xl,
    const u16* __restrict__ Wh, const u16* __restrict__ Wl,
    const float* __restrict__ eb, const float* __restrict__ wts,
    const int* __restrict__ lists, const int* __restrict__ ntiles,
    const int4* __restrict__ table, float* __restrict__ out) {
  int tm = blockIdx.x >> 3, tn = blockIdx.x & 7;   // tn == XCD (bid%8): B-panel
  if (tm >= ntiles[slot]) return;                  // locality per XCD as in round 2
  int4 ent = table[slot * NTM + tm];
  int e = ent.x, start = ent.y, rows = ent.z;
  int n0 = tn * 128;

  __shared__ __align__(16) u16 Al[2][BM * BK];   // 2 x 8 KB
  __shared__ __align__(16) u16 Bl[2][BM * BK];   // 2 x 8 KB
  __shared__ int   tok[BM];
  __shared__ float wt[BM];

  int tid = threadIdx.x;
  if (tid < BM) {
    int t = 0; float w = 0.f;
    if (tid < rows) {
      t = lists[slot * N_TOK + start + tid];
      w = wts[t * 2 + slot];
    }
    tok[tid] = t; wt[tid] = w;
  }
  __syncthreads();

  int lane = tid & 63, wid = tid >> 6;
  // staging: idx = half*256 + tid -> row idx>>2, 8-elem seg (idx&3)*8
  // LDS byte addr = half*4096 + wid*1024 + lane*16 (linear, matches rows)
  int r0 = tid >> 2, seg = (tid & 3) * 8;
  int r1 = (tid + 256) >> 2;
  size_t aoff0 = (size_t)tok[r0] * DIM + seg;
  size_t aoff1 = (size_t)tok[r1] * DIM + seg;
  size_t boff0 = ((size_t)e * DIM + (n0 + r0)) * DIM + seg;
  size_t boff1 = ((size_t)e * DIM + (n0 + r1)) * DIM + seg;

  char* A0 = (char*)&Al[0][0];
  char* B0 = (char*)&Bl[0][0];

  f32x4 acc[4][4] = {};
  int wm = wid >> 1, wn = wid & 1;
  int lrow = lane & 15, lk = (lane >> 4) * 8;

  // prologue: stage K-step 0 into buf 0
  {
    gload_lds16(A0 +        wid * 1024, xh + aoff0);
    gload_lds16(A0 + 4096 + wid * 1024, xh + aoff1);
    gload_lds16(B0 +        wid * 1024, Wh + boff0);
    gload_lds16(B0 + 4096 + wid * 1024, Wh + boff1);
  }
  __syncthreads();   // drains vmcnt(0): buf 0 ready

  int cur = 0;
#pragma unroll 1
  for (int kt = 0; kt < 96; ++kt) {
    // ---- stage kt+1 into buf^1 (issued BEFORE compute; latency hides) ----
    int ks = kt + 1; if (ks > 95) ks = 95;     // last dup-stage is harmless
    {
      int term = ks >> 5;
      int colE = (ks & 31) * BK;
      const u16* asrc = ((term == 2) ? xl : xh) + colE;
      const u16* bsrc = ((term == 1) ? Wl : Wh) + colE;
      char* dA = A0 + (cur ^ 1) * 8192;
      char* dB = B0 + (cur ^ 1) * 8192;
      gload_lds16(dA +        wid * 1024, asrc + aoff0);
      gload_lds16(dA + 4096 + wid * 1024, asrc + aoff1);
      gload_lds16(dB +        wid * 1024, bsrc + boff0);
      gload_lds16(dB + 4096 + wid * 1024, bsrc + boff1);
    }
    // ---- compute kt from buf[cur] ----
    const u16* As = &Al[cur][0];
    const u16* Bs = &Bl[cur][0];
    short8 a[4], b[4];
#pragma unroll
    for (int mi = 0; mi < 4; ++mi)
      a[mi] = *(const short8*)&As[(wm * 64 + mi * 16 + lrow) * BK + lk];
#pragma unroll
    for (int ni = 0; ni < 4; ++ni)
      b[ni] = *(const short8*)&Bs[(wn * 64 + ni * 16 + lrow) * BK + lk];
#pragma unroll
    for (int mi = 0; mi < 4; ++mi)
#pragma unroll
      for (int ni = 0; ni < 4; ++ni)
        acc[mi][ni] = __builtin_amdgcn_mfma_f32_16x16x32_bf16(
            a[mi], b[ni], acc[mi][ni], 0, 0, 0);
    __syncthreads();   // one barrier/step: drains vmcnt -> buf^1 staged; WAR-safe
    cur ^= 1;
  }

  // epilogue: out[t] (slot0) = w*(acc+bias); slot1: +=
#pragma unroll
  for (int mi = 0; mi < 4; ++mi) {
    int rbase = wm * 64 + mi * 16 + (lane >> 4) * 4;
#pragma unroll
    for (int ni = 0; ni < 4; ++ni) {
      int c = n0 + wn * 64 + ni * 16 + (lane & 15);
      float bv = eb[e * DIM + c];
#pragma unroll
      for (int j = 0; j < 4; ++j) {
        int r = rbase + j;
        if (r < rows) {
          float v = wt[r] * (acc[mi][ni][j] + bv);
          size_t oidx = (size_t)tok[r] * DIM + c;
          if (slot == 0) out[oidx] = v;
          else           out[oidx] += v;
        }
      }
    }
  }
}

// ---------------- launch ----------------
extern "C" void kernel_launch(void* const* d_in, const int* in_sizes, int n_in,
                              void* d_out, int out_size, void* d_ws, size_t ws_size,
                              hipStream_t stream) {
  const float* x  = (const float*)d_in[0];
  const float* gW = (const float*)d_in[1];
  const float* gb = (const float*)d_in[2];
  const float* eW = (const float*)d_in[3];
  const float* eb = (const float*)d_in[4];
  float* out = (float*)d_out;

  char* ws = (char*)d_ws;
  size_t o = 0;
  u16* xh = (u16*)(ws + o); o += (size_t)N_TOK * DIM * 2;      //  64 MiB
  u16* xl = (u16*)(ws + o); o += (size_t)N_TOK * DIM * 2;      //  64 MiB
  u16* Wh = (u16*)(ws + o); o += (size_t)NEXP * DIM * DIM * 2; //  16 MiB
  u16* Wl = (u16*)(ws + o); o += (size_t)NEXP * DIM * DIM * 2; //  16 MiB
  float* wts = (float*)(ws + o); o += (size_t)N_TOK * 2 * 4;
  int* eids  = (int*)(ws + o);   o += (size_t)N_TOK * 2 * 4;
  int* lists = (int*)(ws + o);   o += (size_t)2 * N_TOK * 4;
  Ctrl* ctrl = (Ctrl*)(ws + o);  o += sizeof(Ctrl);

  k_convert_w<<<2048, 256, 0, stream>>>((const float4*)eW, (ushort4*)Wh,
                                        (ushort4*)Wl, ctrl->counts);
  k_gate<<<512, 256, 0, stream>>>(x, gW, gb, xh, xl, wts, eids, ctrl->counts);
  k_scan<<<1, 64, 0, stream>>>(ctrl);
  k_lists<<<N_TOK / 256, 256, 0, stream>>>(eids, ctrl->cursors, lists);
  k_gemm<<<NTM * 8, 256, 0, stream>>>(0, xh, xl, Wh, Wl, eb, wts, lists,
                                      ctrl->ntiles, ctrl->table, out);
  k_gemm<<<NTM * 8, 256, 0, stream>>>(1, xh, xl, Wh, Wl, eb, wts, lists,
                                      ctrl->ntiles, ctrl->table, out);
}

// Round 10
// 1088.520 us; speedup vs baseline: 1.3502x; 1.1294x over previous
//
#include <hip/hip_runtime.h>
#include <hip/hip_bf16.h>
#include <cstdint>

// MoE top-2 of 8, N=32768 tokens, D=1024.
// fp32 -> (bf16 hi, lo) split; out = hi*Wh + hi*Wl + lo*Wh, K_eff = 3*1024.
// Grouped GEMM: 128x128 tile, BK=64 (two 32-K half-slabs in LDS), single
// buffer, 2 barriers per 64-K step (m97 structure, round-2 proven; drain
// amortized over 2x compute vs round-2). Two passes (slot0 =, slot1 +=).

#define N_TOK 32768
#define DIM   1024
#define NEXP  8
#define BM    128
#define NTM   263           // max sum_e ceil(n_e/128)

typedef __attribute__((ext_vector_type(8))) short short8;   // 8 bf16
typedef __attribute__((ext_vector_type(4))) float f32x4;
typedef unsigned short u16;

struct Ctrl {
  int counts[16];      // [slot][expert] -- zeroed by k_convert_w each launch
  int cursors[16];
  int ntiles[2];
  int pad[30];
  int4 table[2 * NTM]; // {expert, start_in_slot_list, rows, 0}
};

__device__ __forceinline__ void gload_lds16(void* lds, const void* g) {
  __builtin_amdgcn_global_load_lds(
      (const __attribute__((address_space(1))) void*)g,
      (__attribute__((address_space(3))) void*)lds, 16, 0, 0);
}

// split: hi = truncate-to-bf16(x); lo = truncate-to-bf16(x - hi)
__device__ __forceinline__ void splitf(float f, u16& h, u16& l) {
  uint32_t u = __float_as_uint(f);
  h = (u16)(u >> 16);
  float r = f - __uint_as_float(u & 0xFFFF0000u);   // exact in f32
  l = (u16)(__float_as_uint(r) >> 16);
}

// ---------------- expert weight conversion (+ ctrl zero) ----------------
extern "C" __global__ __launch_bounds__(256) void k_convert_w(
    const float4* __restrict__ W, ushort4* __restrict__ Wh,
    ushort4* __restrict__ Wl, int* __restrict__ counts) {
  if (blockIdx.x == 0 && threadIdx.x < 16) counts[threadIdx.x] = 0;
  const int total = NEXP * DIM * DIM / 4;
  for (int i = blockIdx.x * 256 + threadIdx.x; i < total; i += gridDim.x * 256) {
    float4 v = W[i];
    u16 hx, lx, hy, ly, hz, lz, hw, lw;
    splitf(v.x, hx, lx); splitf(v.y, hy, ly);
    splitf(v.z, hz, lz); splitf(v.w, hw, lw);
    Wh[i] = make_ushort4(hx, hy, hz, hw);
    Wl[i] = make_ushort4(lx, ly, lz, lw);
  }
}

// ---------------- gating + x conversion (fused) ----------------
extern "C" __global__ __launch_bounds__(256) void k_gate(
    const float* __restrict__ x, const float* __restrict__ gW,
    const float* __restrict__ gb, u16* __restrict__ xh, u16* __restrict__ xl,
    float* __restrict__ wts, int* __restrict__ eids, int* __restrict__ counts) {
  __shared__ float4 gwl[NEXP * 256];
  __shared__ int cnt[16];
  int tid = threadIdx.x;
  for (int i = tid; i < NEXP * 256; i += 256) gwl[i] = ((const float4*)gW)[i];
  if (tid < 16) cnt[tid] = 0;
  __syncthreads();

  float gbr[NEXP];
#pragma unroll
  for (int e = 0; e < NEXP; ++e) gbr[e] = gb[e];

  int lane = tid & 63, wid = tid >> 6;
  int wave = blockIdx.x * 4 + wid;
  for (int t = wave; t < N_TOK; t += 2048) {
    const float4* xr = (const float4*)(x + (size_t)t * DIM);
    float acc[NEXP] = {0,0,0,0,0,0,0,0};
    float4 xv[4];
#pragma unroll
    for (int j = 0; j < 4; ++j) {
      float4 v = xr[j * 64 + lane];
      xv[j] = v;
#pragma unroll
      for (int e = 0; e < NEXP; ++e) {
        float4 g = gwl[e * 256 + j * 64 + lane];
        acc[e] += v.x * g.x + v.y * g.y + v.z * g.z + v.w * g.w;
      }
    }
#pragma unroll
    for (int off = 32; off > 0; off >>= 1)
#pragma unroll
      for (int e = 0; e < NEXP; ++e) acc[e] += __shfl_xor(acc[e], off, 64);

#pragma unroll
    for (int e = 0; e < NEXP; ++e) acc[e] += gbr[e];

    float m = acc[0];
#pragma unroll
    for (int e = 1; e < NEXP; ++e) m = fmaxf(m, acc[e]);
    float p[NEXP], s = 0.f;
#pragma unroll
    for (int e = 0; e < NEXP; ++e) { p[e] = expf(acc[e] - m); s += p[e]; }
    float inv = 1.f / s;

    int i0 = 0; float b0 = acc[0];
#pragma unroll
    for (int e = 1; e < NEXP; ++e) if (acc[e] > b0) { b0 = acc[e]; i0 = e; }
    int i1 = -1; float b1 = -3.4e38f;
#pragma unroll
    for (int e = 0; e < NEXP; ++e)
      if (e != i0 && acc[e] > b1) { b1 = acc[e]; i1 = e; }

    if (lane == 0) {
      wts[t * 2 + 0] = p[i0] * inv;
      wts[t * 2 + 1] = p[i1] * inv;
      eids[t * 2 + 0] = i0;
      eids[t * 2 + 1] = i1;
      atomicAdd(&cnt[i0], 1);
      atomicAdd(&cnt[8 + i1], 1);
    }
    ushort4* oh = (ushort4*)(xh + (size_t)t * DIM);
    ushort4* ol = (ushort4*)(xl + (size_t)t * DIM);
#pragma unroll
    for (int j = 0; j < 4; ++j) {
      u16 hx, lx, hy, ly, hz, lz, hw, lw;
      splitf(xv[j].x, hx, lx); splitf(xv[j].y, hy, ly);
      splitf(xv[j].z, hz, lz); splitf(xv[j].w, hw, lw);
      oh[j * 64 + lane] = make_ushort4(hx, hy, hz, hw);
      ol[j * 64 + lane] = make_ushort4(lx, ly, lz, lw);
    }
  }
  __syncthreads();
  if (tid < 16) atomicAdd(&counts[tid], cnt[tid]);
}

// ---------------- scan + tile schedule (BM=128) ----------------
extern "C" __global__ void k_scan(Ctrl* ctrl) {
  if (threadIdx.x == 0) {
    for (int s = 0; s < 2; ++s) {
      int off = 0, nt = 0;
      for (int e = 0; e < NEXP; ++e) {
        int c = ctrl->counts[s * 8 + e];
        ctrl->cursors[s * 8 + e] = off;
        int tcnt = (c + BM - 1) >> 7;
        for (int i = 0; i < tcnt; ++i)
          ctrl->table[s * NTM + nt + i] =
              make_int4(e, off + i * BM, min(BM, c - i * BM), 0);
        nt += tcnt; off += c;
      }
      ctrl->ntiles[s] = nt;
    }
  }
}

// ---------------- build per-(slot,expert) token lists ----------------
extern "C" __global__ __launch_bounds__(256) void k_lists(
    const int* __restrict__ eids, int* __restrict__ cursors, int* __restrict__ lists) {
  int t = blockIdx.x * 256 + threadIdx.x;
  int lane = threadIdx.x & 63;
#pragma unroll
  for (int s = 0; s < 2; ++s) {
    int e = eids[t * 2 + s];
#pragma unroll
    for (int ex = 0; ex < NEXP; ++ex) {
      unsigned long long msk = __ballot(e == ex);
      if (msk) {
        int leader = __ffsll((unsigned long long)msk) - 1;
        int base = 0;
        if (lane == leader) base = atomicAdd(&cursors[s * 8 + ex], (int)__popcll(msk));
        base = __shfl(base, leader, 64);
        if (e == ex) {
          int pos = base + (int)__popcll(msk & ((1ull << lane) - 1ull));
          lists[s * N_TOK + pos] = t;
        }
      }
    }
  }
}

// ---------------- grouped GEMM (one slot per launch) ----------------
// 128x128 tile; BK=64 as two [128][32] half-slabs; 48 K-steps
// (3 split-terms x 16). m97 2-barrier structure, single buffer.
extern "C" __global__ __launch_bounds__(256) void k_gemm(
    int slot, const u16* __restrict__ xh, const u16* __restrict__ xl,
    const u16* __restrict__ Wh, const u16* __restrict__ Wl,
    const float* __restrict__ eb, const float* __restrict__ wts,
    const int* __restrict__ lists, const int* __restrict__ ntiles,
    const int4* __restrict__ table, float* __restrict__ out) {
  int tm = blockIdx.x >> 3, tn = blockIdx.x & 7;   // tn == XCD: B-panel/XCD locality
  if (tm >= ntiles[slot]) return;
  int4 ent = table[slot * NTM + tm];
  int e = ent.x, start = ent.y, rows = ent.z;
  int n0 = tn * 128;

  __shared__ __align__(16) u16 Al[2][BM * 32];   // k-half-major, 2 x 8 KB
  __shared__ __align__(16) u16 Bl[2][BM * 32];   // 2 x 8 KB
  __shared__ int   tok[BM];
  __shared__ float wt[BM];

  int tid = threadIdx.x;
  if (tid < BM) {
    int t = 0; float w = 0.f;
    if (tid < rows) {
      t = lists[slot * N_TOK + start + tid];
      w = wts[t * 2 + slot];
    }
    tok[tid] = t; wt[tid] = w;
  }
  __syncthreads();

  int lane = tid & 63, wid = tid >> 6;
  // staging (per half-slab, round-2 pattern): idx = half*256+tid ->
  // row idx>>2, 8-elem seg (idx&3)*8; LDS byte = half*4096 + wid*1024 + lane*16
  int r0 = tid >> 2, seg = (tid & 3) * 8;
  int r1 = (tid + 256) >> 2;
  size_t aoff0 = (size_t)tok[r0] * DIM + seg;
  size_t aoff1 = (size_t)tok[r1] * DIM + seg;
  size_t boff0 = ((size_t)e * DIM + (n0 + r0)) * DIM + seg;
  size_t boff1 = ((size_t)e * DIM + (n0 + r1)) * DIM + seg;

  f32x4 acc[4][4] = {};
  int wm = wid >> 1, wn = wid & 1;
  int lrow = lane & 15, lk = (lane >> 4) * 8;

#pragma unroll 1
  for (int term = 0; term < 3; ++term) {
    const u16* asrc = (term == 2) ? xl : xh;
    const u16* bsrc = (term == 1) ? Wl : Wh;
    const u16* ap0 = asrc + aoff0;
    const u16* ap1 = asrc + aoff1;
    const u16* bp0 = bsrc + boff0;
    const u16* bp1 = bsrc + boff1;
#pragma unroll 1
    for (int col = 0; col < DIM; col += 64) {
      // stage k-half 0 (cols col..col+31) and k-half 1 (col+32..col+63)
#pragma unroll
      for (int h = 0; h < 2; ++h) {
        char* dA = (char*)&Al[h][0] + wid * 1024;
        char* dB = (char*)&Bl[h][0] + wid * 1024;
        int c = col + h * 32;
        gload_lds16(dA,        ap0 + c);
        gload_lds16(dA + 4096, ap1 + c);
        gload_lds16(dB,        bp0 + c);
        gload_lds16(dB + 4096, bp1 + c);
      }
      __syncthreads();   // drains vmcnt before s_barrier: both halves ready

#pragma unroll
      for (int h = 0; h < 2; ++h) {
        const u16* As = &Al[h][0];
        const u16* Bs = &Bl[h][0];
        short8 a[4], b[4];
#pragma unroll
        for (int mi = 0; mi < 4; ++mi)
          a[mi] = *(const short8*)&As[(wm * 64 + mi * 16 + lrow) * 32 + lk];
#pragma unroll
        for (int ni = 0; ni < 4; ++ni)
          b[ni] = *(const short8*)&Bs[(wn * 64 + ni * 16 + lrow) * 32 + lk];
#pragma unroll
        for (int mi = 0; mi < 4; ++mi)
#pragma unroll
          for (int ni = 0; ni < 4; ++ni)
            acc[mi][ni] = __builtin_amdgcn_mfma_f32_16x16x32_bf16(
                a[mi], b[ni], acc[mi][ni], 0, 0, 0);
      }
      __syncthreads();
    }
  }

  // epilogue: out[t] (slot0) = w*(acc+bias); slot1: +=
#pragma unroll
  for (int mi = 0; mi < 4; ++mi) {
    int rbase = wm * 64 + mi * 16 + (lane >> 4) * 4;
#pragma unroll
    for (int ni = 0; ni < 4; ++ni) {
      int c = n0 + wn * 64 + ni * 16 + (lane & 15);
      float bv = eb[e * DIM + c];
#pragma unroll
      for (int j = 0; j < 4; ++j) {
        int r = rbase + j;
        if (r < rows) {
          float v = wt[r] * (acc[mi][ni][j] + bv);
          size_t oidx = (size_t)tok[r] * DIM + c;
          if (slot == 0) out[oidx] = v;
          else           out[oidx] += v;
        }
      }
    }
  }
}

// ---------------- launch ----------------
extern "C" void kernel_launch(void* const* d_in, const int* in_sizes, int n_in,
                              void* d_out, int out_size, void* d_ws, size_t ws_size,
                              hipStream_t stream) {
  const float* x  = (const float*)d_in[0];
  const float* gW = (const float*)d_in[1];
  const float* gb = (const float*)d_in[2];
  const float* eW = (const float*)d_in[3];
  const float* eb = (const float*)d_in[4];
  float* out = (float*)d_out;

  char* ws = (char*)d_ws;
  size_t o = 0;
  u16* xh = (u16*)(ws + o); o += (size_t)N_TOK * DIM * 2;      //  64 MiB
  u16* xl = (u16*)(ws + o); o += (size_t)N_TOK * DIM * 2;      //  64 MiB
  u16* Wh = (u16*)(ws + o); o += (size_t)NEXP * DIM * DIM * 2; //  16 MiB
  u16* Wl = (u16*)(ws + o); o += (size_t)NEXP * DIM * DIM * 2; //  16 MiB
  float* wts = (float*)(ws + o); o += (size_t)N_TOK * 2 * 4;
  int* eids  = (int*)(ws + o);   o += (size_t)N_TOK * 2 * 4;
  int* lists = (int*)(ws + o);   o += (size_t)2 * N_TOK * 4;
  Ctrl* ctrl = (Ctrl*)(ws + o);  o += sizeof(Ctrl);

  k_convert_w<<<2048, 256, 0, stream>>>((const float4*)eW, (ushort4*)Wh,
                                        (ushort4*)Wl, ctrl->counts);
  k_gate<<<512, 256, 0, stream>>>(x, gW, gb, xh, xl, wts, eids, ctrl->counts);
  k_scan<<<1, 64, 0, stream>>>(ctrl);
  k_lists<<<N_TOK / 256, 256, 0, stream>>>(eids, ctrl->cursors, lists);
  k_gemm<<<NTM * 8, 256, 0, stream>>>(0, xh, xl, Wh, Wl, eb, wts, lists,
                                      ctrl->ntiles, ctrl->table, out);
  k_gemm<<<NTM * 8, 256, 0, stream>>>(1, xh, xl, Wh, Wl, eb, wts, lists,
                                      ctrl->ntiles, ctrl->table, out);
}